// Round 7
// baseline (246.961 us; speedup 1.0000x reference)
//
#include <hip/hip_runtime.h>
#include <cstdint>

#define C_DIM 512
#define T_DIM 400
#define KW 31
#define TOUT 400
#define WSROW 432        // padded time index t+k in [0,430] -> 432
#define TPB 256
#define PPB 64           // (c,t) pairs per block; 4 k-split lanes each
#define ROWB 48          // LUT row stride in bytes (12 floats)
#define ZOFF (257 * ROWB)// zero-row byte offset (kills lane3 k=31 contribution)

#define WSQ_BYTES (C_DIM * WSROW * 8)            // 1,769,472
#define RT_OFF    WSQ_BYTES
#define RT_BYTES  ((C_DIM * KW + 1) * 16)        // +1 zeroed pad row
#define WS_NEEDED (WSQ_BYTES + RT_BYTES)

typedef float f2 __attribute__((ext_vector_type(2)));

// ---------------- host threefry2x32 (key-chain computation, pure CPU) --------
static inline uint32_t h_rotl32(uint32_t x, int d){ return (x<<d)|(x>>(32-d)); }

static void h_threefry2x32(uint32_t k0, uint32_t k1, uint32_t x0, uint32_t x1,
                           uint32_t* o0, uint32_t* o1){
  uint32_t ks2 = k0 ^ k1 ^ 0x1BD11BDAu;
  uint32_t ks[3] = {k0, k1, ks2};
  const int rotA[4] = {13,15,26,6};
  const int rotB[4] = {17,29,16,24};
  uint32_t v0 = x0 + k0, v1 = x1 + k1;
  for (int r = 0; r < 5; ++r){
    const int* rot = (r & 1) ? rotB : rotA;
    for (int q = 0; q < 4; ++q){
      v0 += v1; v1 = h_rotl32(v1, rot[q]); v1 ^= v0;
    }
    v0 += ks[(r+1)%3];
    v1 += ks[(r+2)%3] + (uint32_t)(r+1);
  }
  *o0 = v0; *o1 = v1;
}

// ---------------- device threefry, 4 independent streams in lockstep --------
template<int R>
__device__ __forceinline__ void tfr4(uint32_t v0[4], uint32_t v1[4]){
  #pragma unroll
  for (int n = 0; n < 4; ++n){
    v0[n] += v1[n];
    v1[n] = (v1[n] << R) | (v1[n] >> (32 - R));   // -> v_alignbit_b32
    v1[n] ^= v0[n];
  }
}

__device__ __forceinline__ void tfinj4(uint32_t v0[4], uint32_t v1[4],
                                       const uint32_t a[4], const uint32_t b[4],
                                       uint32_t cadd){
  #pragma unroll
  for (int n = 0; n < 4; ++n){ v0[n] += a[n]; v1[n] += b[n] + cadd; }
}

__device__ __forceinline__ void threefry_xor4(const uint32_t ka[4], const uint32_t kb[4],
                                              uint32_t j, uint32_t out[4]){
  uint32_t ks2[4], v0[4], v1[4];
  #pragma unroll
  for (int n = 0; n < 4; ++n){
    ks2[n] = ka[n] ^ kb[n] ^ 0x1BD11BDAu;
    v0[n] = ka[n];            // x0 = 0
    v1[n] = j + kb[n];        // x1 = j
  }
  tfr4<13>(v0,v1); tfr4<15>(v0,v1); tfr4<26>(v0,v1); tfr4<6>(v0,v1);
  tfinj4(v0,v1,kb,ks2,1u);
  tfr4<17>(v0,v1); tfr4<29>(v0,v1); tfr4<16>(v0,v1); tfr4<24>(v0,v1);
  tfinj4(v0,v1,ks2,ka,2u);
  tfr4<13>(v0,v1); tfr4<15>(v0,v1); tfr4<26>(v0,v1); tfr4<6>(v0,v1);
  tfinj4(v0,v1,ka,kb,3u);
  tfr4<17>(v0,v1); tfr4<29>(v0,v1); tfr4<16>(v0,v1); tfr4<24>(v0,v1);
  tfinj4(v0,v1,kb,ks2,4u);
  tfr4<13>(v0,v1); tfr4<15>(v0,v1); tfr4<26>(v0,v1); tfr4<6>(v0,v1);
  tfinj4(v0,v1,ks2,ka,5u);
  #pragma unroll
  for (int n = 0; n < 4; ++n) out[n] = v0[n] ^ v1[n];
}

// high-branch (rare) scalar erfinv tail: returns p such that erfinv = p*x
__device__ __forceinline__ float erfinv_hi(float w){
  float ws = __builtin_amdgcn_sqrtf(w) - 3.0f;
  float p =             -0.000200214257f;
  p = fmaf(p, ws,   0.000100950558f);
  p = fmaf(p, ws,   0.00134934322f);
  p = fmaf(p, ws,  -0.00367342844f);
  p = fmaf(p, ws,   0.00573950773f);
  p = fmaf(p, ws,  -0.0076224613f);
  p = fmaf(p, ws,   0.00943887047f);
  p = fmaf(p, ws,   1.00167406f);
  p = fmaf(p, ws,   2.83297682f);
  return p;
}

// ------- pre-pass 1: DAC-quantize x once per (c,time), store LDS byte offs --
__global__ __launch_bounds__(256) void dac_prepass(
    const float* __restrict__ x, uint2* __restrict__ wsq)
{
  const int m = blockIdx.x * 256 + threadIdx.x;      // exact over C_DIM*WSROW
  const int c  = m / WSROW;
  const int tp = m - c * WSROW;
  const int time = tp - 15;
  const bool inb = (time >= 0) && (time < T_DIM);
  uint32_t off[4];
  #pragma unroll
  for (int b = 0; b < 4; ++b){
    float xv = inb ? x[(b * C_DIM + c) * T_DIM + time] : 0.0f;
    float q = rintf(xv * 128.0f);
    q = fminf(fmaxf(q, -128.0f), 128.0f);
    off[b] = (uint32_t)(((int)q + 128) * ROWB);      // LDS byte offset
  }
  wsq[m] = make_uint2(off[0] | (off[1] << 16), off[2] | (off[3] << 16));
}

// ------- pre-pass 2: transpose r to (c, k, is) float4; zero the pad row -----
__global__ __launch_bounds__(256) void r_prepass(
    const float* __restrict__ r, float4* __restrict__ rT)
{
  const int m = blockIdx.x * 256 + threadIdx.x;      // over C_DIM*KW + 1
  if (m > C_DIM * KW) return;
  if (m == C_DIM * KW){                              // zero pad row (lane3 k=31)
    rT[m] = make_float4(0.0f, 0.0f, 0.0f, 0.0f);
    return;
  }
  const int c = m / KW;
  const int k = m - c * KW;
  float4 v;
  v.x = r[(0 * C_DIM + c) * KW + k];
  v.y = r[(1 * C_DIM + c) * KW + k];
  v.z = r[(2 * C_DIM + c) * KW + k];
  v.w = r[(3 * C_DIM + c) * KW + k];
  rT[m] = v;
}

// ---------------- main kernel ----------------------------------------------
template<bool USE_WS>
__global__ __launch_bounds__(TPB, 5) void memristor_main(
    const float* __restrict__ x,
    const float* __restrict__ poly_low,   // (2,2,7)
    const float* __restrict__ poly_high,  // (2,2,6)
    const float* __restrict__ r,          // (2,2,C,K)
    const float* __restrict__ bias,
    const uint2* __restrict__ wsq,        // (C, WSROW) packed u16 byte-offs x4
    const float4* __restrict__ rT,        // (C, K) -> (r0,r1,r2,r3), +pad row
    float* __restrict__ out,              // (B,C,TOUT)
    uint32_t nk0a, uint32_t nk0b, uint32_t nk1a, uint32_t nk1b,
    uint32_t nk2a, uint32_t nk2b, uint32_t nk3a, uint32_t nk3b)
{
  // row = 12 floats: [lo0,lo1,d0,d1, lo2,lo3,d2,d3, sj*sqrt2, pad x3]
  // row 257 is all-zero: routing an access there contributes exactly 0.
  __shared__ __align__(16) float lut[258 * 12];

  const int tid = threadIdx.x;

  for (int qi = tid; qi < 258; qi += TPB){
    if (qi == 257){
      #pragma unroll
      for (int j = 0; j < 12; ++j) lut[qi*12 + j] = 0.0f;
    } else {
      const float q = (float)(qi - 128);
      const float w = (q * 0.0078125f) * 0.6f;
      float lov[4], div[4];
      #pragma unroll
      for (int is = 0; is < 4; ++is){
        const float* pl = poly_low  + is * 7;
        const float* ph = poly_high + is * 6;
        float lo = pl[6];
        lo = fmaf(lo, w, pl[5]); lo = fmaf(lo, w, pl[4]); lo = fmaf(lo, w, pl[3]);
        lo = fmaf(lo, w, pl[2]); lo = fmaf(lo, w, pl[1]); lo = fmaf(lo, w, pl[0]);
        float hi = ph[5];
        hi = fmaf(hi, w, ph[4]); hi = fmaf(hi, w, ph[3]); hi = fmaf(hi, w, ph[2]);
        hi = fmaf(hi, w, ph[1]); hi = fmaf(hi, w, ph[0]);
        lov[is] = lo; div[is] = hi - lo;
      }
      lut[qi*12 + 0] = lov[0]; lut[qi*12 + 1] = lov[1];
      lut[qi*12 + 2] = div[0]; lut[qi*12 + 3] = div[1];
      lut[qi*12 + 4] = lov[2]; lut[qi*12 + 5] = lov[3];
      lut[qi*12 + 6] = div[2]; lut[qi*12 + 7] = div[3];
      const float jf = fmaf(1.6567788e-28f,
                            __builtin_amdgcn_rcpf(fabsf(w) + 1e-12f),
                            5.4365637e-08f);
      lut[qi*12 + 8] = __builtin_amdgcn_sqrtf(jf) * 1.41421356f; // sqrt2 folded
    }
  }
  __syncthreads();

  // 4 lanes per (c,t): lane l covers k in [8l, 8l+8) (lane3 k=31 is zero-gated)
  const int l   = tid & 3;
  const int p   = tid >> 2;
  const int gid = blockIdx.x * PPB + p;     // exact: grid*PPB == C*TOUT
  const int c   = gid / TOUT;
  const int t   = gid - c * TOUT;
  const int k0  = l * 8;

  const uint32_t ka[4] = {nk0a, nk1a, nk2a, nk3a};
  const uint32_t kb[4] = {nk0b, nk1b, nk2b, nk3b};
  const uint32_t jbase = (uint32_t)((t * C_DIM + c) * KW) + (uint32_t)k0;

  f2 acc01[4], acc23[4];                    // [b], packed over is-pairs
  #pragma unroll
  for (int b = 0; b < 4; ++b){ acc01[b] = (f2)(0.0f); acc23[b] = (f2)(0.0f); }

  auto compute = [&](uint32_t off0, uint32_t off1, uint32_t off2, uint32_t off3,
                     f2 rr01, f2 rr23, uint32_t jj){
    uint32_t bits[4];
    threefry_xor4(ka, kb, jj, bits);

    // ---- packed u -> x, (1-x)(1+x) (validated R5/R6 math, NaN-safe) ----
    const f2 u01 = { __uint_as_float((bits[0] >> 9) | 0x3f800000u),
                     __uint_as_float((bits[1] >> 9) | 0x3f800000u) };
    const f2 u23 = { __uint_as_float((bits[2] >> 9) | 0x3f800000u),
                     __uint_as_float((bits[3] >> 9) | 0x3f800000u) };
    const float LO = -0.99999994f;
    const f2 u1_01 = u01 - 1.0f, u1_23 = u23 - 1.0f;
    const f2 x01 = u1_01 * 2.0f + LO;
    const f2 x23 = u1_23 * 2.0f + LO;
    const f2 a01 = u1_01 * (-2.0f) + 1.99999994f;   // 1-x
    const f2 a23 = u1_23 * (-2.0f) + 1.99999994f;
    const f2 b01 = u1_01 * 2.0f + 5.9604645e-8f;    // 1+x
    const f2 b23 = u1_23 * 2.0f + 5.9604645e-8f;
    const f2 pr01 = a01 * b01, pr23 = a23 * b23;

    const f2 L01 = { __builtin_amdgcn_logf(pr01.x),
                     __builtin_amdgcn_logf(pr01.y) };
    const f2 L23 = { __builtin_amdgcn_logf(pr23.x),
                     __builtin_amdgcn_logf(pr23.y) };
    const f2 t01 = L01 * (-0.69314718f) + (-2.5f);
    const f2 t23 = L23 * (-0.69314718f) + (-2.5f);

    f2 p01 = (f2)(2.81022636e-08f), p23 = (f2)(2.81022636e-08f);
    p01 = p01*t01 + 3.43273939e-07f;  p23 = p23*t23 + 3.43273939e-07f;
    p01 = p01*t01 + -3.5233877e-06f;  p23 = p23*t23 + -3.5233877e-06f;
    p01 = p01*t01 + -4.39150654e-06f; p23 = p23*t23 + -4.39150654e-06f;
    p01 = p01*t01 + 0.00021858087f;   p23 = p23*t23 + 0.00021858087f;
    p01 = p01*t01 + -0.00125372503f;  p23 = p23*t23 + -0.00125372503f;
    p01 = p01*t01 + -0.00417768164f;  p23 = p23*t23 + -0.00417768164f;
    p01 = p01*t01 + 0.246640727f;     p23 = p23*t23 + 0.246640727f;
    p01 = p01*t01 + 1.50140941f;      p23 = p23*t23 + 1.50140941f;

    // rare tail fixups: w >= 5  <=>  L <= -5/ln2
    const float LTH = -7.2134752f;
    if (L01.x <= LTH) p01.x = erfinv_hi(L01.x * -0.69314718f);
    if (L01.y <= LTH) p01.y = erfinv_hi(L01.y * -0.69314718f);
    if (L23.x <= LTH) p23.x = erfinv_hi(L23.x * -0.69314718f);
    if (L23.y <= LTH) p23.y = erfinv_hi(L23.y * -0.69314718f);

    const f2 noise01 = p01 * x01;     // sqrt2 folded into LUT sj
    const f2 noise23 = p23 * x23;

    #pragma unroll
    for (int b = 0; b < 4; ++b){
      const uint32_t off = (b == 0) ? off0 : (b == 1) ? off1 : (b == 2) ? off2 : off3;
      const float* row = (const float*)((const char*)lut + off);
      const float4 A  = *(const float4*)(row);      // lo0,lo1,d0,d1
      const float4 Bv = *(const float4*)(row + 4);  // lo2,lo3,d2,d3
      const float sj  = row[8];
      const f2 lo01 = {A.x, A.y},  d01 = {A.z, A.w};
      const f2 lo23 = {Bv.x, Bv.y}, d23 = {Bv.z, Bv.w};
      const f2 raw01 = d01 * rr01 + lo01;           // pk_fma
      const f2 raw23 = d23 * rr23 + lo23;
      const f2 s01 = { __builtin_amdgcn_sqrtf(fabsf(raw01.x)),
                       __builtin_amdgcn_sqrtf(fabsf(raw01.y)) };
      const f2 s23 = { __builtin_amdgcn_sqrtf(fabsf(raw23.x)),
                       __builtin_amdgcn_sqrtf(fabsf(raw23.y)) };
      const f2 nsj01 = noise01 * sj;
      const f2 nsj23 = noise23 * sj;
      acc01[b] = nsj01 * s01 + (acc01[b] + raw01);
      acc23[b] = nsj23 * s23 + (acc23[b] + raw23);
    }
  };

  if (USE_WS){
    const uint2*  wp = wsq + c * WSROW + t + k0;
    const float4* rp = rT + c * KW + k0;    // lane3 kk=7 hits zeroed pad row
    #pragma unroll 4
    for (int kk = 0; kk < 8; ++kk){
      const uint2  ld = wp[kk];
      const float4 rv = rp[kk];
      uint32_t off0 = ld.x & 0xFFFFu, off1 = ld.x >> 16;
      uint32_t off2 = ld.y & 0xFFFFu, off3 = ld.y >> 16;
      const bool inval = (kk == 7) && (l == 3);     // k=31 doesn't exist
      if (inval){ off0 = ZOFF; off1 = ZOFF; off2 = ZOFF; off3 = ZOFF; }
      compute(off0, off1, off2, off3,
              (f2){rv.x, rv.y}, (f2){rv.z, rv.w}, jbase + (uint32_t)kk);
    }
  } else {
    const int kn = (l == 3) ? 7 : 8;
    for (int kk = 0; kk < kn; ++kk){
      const int k = k0 + kk;
      const int time = t + k - 15;
      const bool inb = (time >= 0) && (time < T_DIM);
      uint32_t off[4];
      #pragma unroll
      for (int b = 0; b < 4; ++b){
        float xv = inb ? x[(b * C_DIM + c) * T_DIM + time] : 0.0f;
        float q = rintf(xv * 128.0f);
        q = fminf(fmaxf(q, -128.0f), 128.0f);
        off[b] = (uint32_t)(((int)q + 128) * ROWB);
      }
      const f2 rr01 = { r[(0 * C_DIM + c) * KW + k], r[(1 * C_DIM + c) * KW + k] };
      const f2 rr23 = { r[(2 * C_DIM + c) * KW + k], r[(3 * C_DIM + c) * KW + k] };
      compute(off[0], off[1], off[2], off[3], rr01, rr23, jbase + (uint32_t)kk);
    }
  }

  // quad butterfly combine: every lane ends with full sums
  const float bv = bias[c];
  #pragma unroll
  for (int b = 0; b < 4; ++b){
    f2 t01 = acc01[b], t23 = acc23[b];
    t01.x += __shfl_xor(t01.x, 1); t01.x += __shfl_xor(t01.x, 2);
    t01.y += __shfl_xor(t01.y, 1); t01.y += __shfl_xor(t01.y, 2);
    t23.x += __shfl_xor(t23.x, 1); t23.x += __shfl_xor(t23.x, 2);
    t23.y += __shfl_xor(t23.y, 1); t23.y += __shfl_xor(t23.y, 2);
    acc01[b] = t01; acc23[b] = t23;
  }

  if (l == 0){
    #pragma unroll
    for (int b = 0; b < 4; ++b){
      float oo = 0.0f;
      {
        const float pair = acc01[b].x - acc01[b].y;   // i=0, weight 2
        float q = rintf((pair * 8020.0f) * 256.0f);
        q = fminf(fmaxf(q, -131072.0f), 131072.0f);
        oo += (q * 0.00390625f) * 2.0f;
      }
      {
        const float pair = acc23[b].x - acc23[b].y;   // i=1, weight 1
        float q = rintf((pair * 8020.0f) * 256.0f);
        q = fminf(fmaxf(q, -131072.0f), 131072.0f);
        oo += (q * 0.00390625f);
      }
      out[(b * C_DIM + c) * TOUT + t] = oo + bv;
    }
  }
}

extern "C" void kernel_launch(void* const* d_in, const int* in_sizes, int n_in,
                              void* d_out, int out_size, void* d_ws, size_t ws_size,
                              hipStream_t stream) {
  const float* x         = (const float*)d_in[0];
  const float* poly_low  = (const float*)d_in[1];
  const float* poly_high = (const float*)d_in[2];
  const float* r         = (const float*)d_in[3];
  const float* bias      = (const float*)d_in[4];
  float* out             = (float*)d_out;

  // key chain: key = jax.random.key(42); 4x (key, nk) = split(key)
  uint32_t ck0 = 0u, ck1 = 42u;
  uint32_t nk[4][2];
  for (int n = 0; n < 4; ++n){
    uint32_t a0, a1, b0, b1;
    h_threefry2x32(ck0, ck1, 0u, 0u, &a0, &a1);  // new key
    h_threefry2x32(ck0, ck1, 0u, 1u, &b0, &b1);  // nk
    nk[n][0] = b0; nk[n][1] = b1;
    ck0 = a0; ck1 = a1;
  }

  const int nblocks = (C_DIM * TOUT) / PPB;      // 3200, exact

  if (ws_size >= (size_t)WS_NEEDED){
    uint2*  wsq = (uint2*)d_ws;
    float4* rT  = (float4*)((char*)d_ws + RT_OFF);
    hipLaunchKernelGGL(dac_prepass, dim3((C_DIM * WSROW) / 256), dim3(256),
                       0, stream, x, wsq);
    hipLaunchKernelGGL(r_prepass, dim3((C_DIM * KW + 256) / 256), dim3(256),
                       0, stream, r, rT);
    hipLaunchKernelGGL((memristor_main<true>), dim3(nblocks), dim3(TPB), 0, stream,
                       x, poly_low, poly_high, r, bias, wsq, rT, out,
                       nk[0][0], nk[0][1], nk[1][0], nk[1][1],
                       nk[2][0], nk[2][1], nk[3][0], nk[3][1]);
  } else {
    hipLaunchKernelGGL((memristor_main<false>), dim3(nblocks), dim3(TPB), 0, stream,
                       x, poly_low, poly_high, r, bias,
                       (const uint2*)nullptr, (const float4*)nullptr, out,
                       nk[0][0], nk[0][1], nk[1][0], nk[1][1],
                       nk[2][0], nk[2][1], nk[3][0], nk[3][1]);
  }
}

// Round 8
// 104.987 us; speedup vs baseline: 2.3523x; 2.3523x over previous
//
#include <hip/hip_runtime.h>
#include <cstdint>

#define C_DIM 512
#define T_DIM 400
#define KW 31
#define TOUT 400
#define WSROW 432        // padded time index t+k in [0,430] -> 432
#define TPB 256
#define PPB 64           // (c,t) pairs per block; 4 k-split lanes each
#define ROWB 48          // LUT row stride in bytes (12 floats)

#define WSQ_BYTES (C_DIM * WSROW * 8)            // 1,769,472
#define RT_OFF    WSQ_BYTES
#define RT_BYTES  (C_DIM * KW * 16)              // 253,952
#define WS_NEEDED (WSQ_BYTES + RT_BYTES)

typedef float f2 __attribute__((ext_vector_type(2)));

// ---------------- host threefry2x32 (key-chain computation, pure CPU) --------
static inline uint32_t h_rotl32(uint32_t x, int d){ return (x<<d)|(x>>(32-d)); }

static void h_threefry2x32(uint32_t k0, uint32_t k1, uint32_t x0, uint32_t x1,
                           uint32_t* o0, uint32_t* o1){
  uint32_t ks2 = k0 ^ k1 ^ 0x1BD11BDAu;
  uint32_t ks[3] = {k0, k1, ks2};
  const int rotA[4] = {13,15,26,6};
  const int rotB[4] = {17,29,16,24};
  uint32_t v0 = x0 + k0, v1 = x1 + k1;
  for (int r = 0; r < 5; ++r){
    const int* rot = (r & 1) ? rotB : rotA;
    for (int q = 0; q < 4; ++q){
      v0 += v1; v1 = h_rotl32(v1, rot[q]); v1 ^= v0;
    }
    v0 += ks[(r+1)%3];
    v1 += ks[(r+2)%3] + (uint32_t)(r+1);
  }
  *o0 = v0; *o1 = v1;
}

// ---------------- device threefry, 4 independent streams in lockstep --------
template<int R>
__device__ __forceinline__ void tfr4(uint32_t v0[4], uint32_t v1[4]){
  #pragma unroll
  for (int n = 0; n < 4; ++n){
    v0[n] += v1[n];
    v1[n] = (v1[n] << R) | (v1[n] >> (32 - R));   // -> v_alignbit_b32
    v1[n] ^= v0[n];
  }
}

__device__ __forceinline__ void tfinj4(uint32_t v0[4], uint32_t v1[4],
                                       const uint32_t a[4], const uint32_t b[4],
                                       uint32_t cadd){
  #pragma unroll
  for (int n = 0; n < 4; ++n){ v0[n] += a[n]; v1[n] += b[n] + cadd; }
}

__device__ __forceinline__ void threefry_xor4(const uint32_t ka[4], const uint32_t kb[4],
                                              uint32_t j, uint32_t out[4]){
  uint32_t ks2[4], v0[4], v1[4];
  #pragma unroll
  for (int n = 0; n < 4; ++n){
    ks2[n] = ka[n] ^ kb[n] ^ 0x1BD11BDAu;
    v0[n] = ka[n];            // x0 = 0
    v1[n] = j + kb[n];        // x1 = j
  }
  tfr4<13>(v0,v1); tfr4<15>(v0,v1); tfr4<26>(v0,v1); tfr4<6>(v0,v1);
  tfinj4(v0,v1,kb,ks2,1u);
  tfr4<17>(v0,v1); tfr4<29>(v0,v1); tfr4<16>(v0,v1); tfr4<24>(v0,v1);
  tfinj4(v0,v1,ks2,ka,2u);
  tfr4<13>(v0,v1); tfr4<15>(v0,v1); tfr4<26>(v0,v1); tfr4<6>(v0,v1);
  tfinj4(v0,v1,ka,kb,3u);
  tfr4<17>(v0,v1); tfr4<29>(v0,v1); tfr4<16>(v0,v1); tfr4<24>(v0,v1);
  tfinj4(v0,v1,kb,ks2,4u);
  tfr4<13>(v0,v1); tfr4<15>(v0,v1); tfr4<26>(v0,v1); tfr4<6>(v0,v1);
  tfinj4(v0,v1,ks2,ka,5u);
  #pragma unroll
  for (int n = 0; n < 4; ++n) out[n] = v0[n] ^ v1[n];
}

// high-branch (rare) scalar erfinv tail: returns p such that erfinv = p*x
__device__ __forceinline__ float erfinv_hi(float w){
  float ws = __builtin_amdgcn_sqrtf(w) - 3.0f;
  float p =             -0.000200214257f;
  p = fmaf(p, ws,   0.000100950558f);
  p = fmaf(p, ws,   0.00134934322f);
  p = fmaf(p, ws,  -0.00367342844f);
  p = fmaf(p, ws,   0.00573950773f);
  p = fmaf(p, ws,  -0.0076224613f);
  p = fmaf(p, ws,   0.00943887047f);
  p = fmaf(p, ws,   1.00167406f);
  p = fmaf(p, ws,   2.83297682f);
  return p;
}

// ------- pre-pass 1: DAC-quantize x once per (c,time), store LDS byte offs --
__global__ __launch_bounds__(256) void dac_prepass(
    const float* __restrict__ x, uint2* __restrict__ wsq)
{
  const int m = blockIdx.x * 256 + threadIdx.x;      // exact over C_DIM*WSROW
  const int c  = m / WSROW;
  const int tp = m - c * WSROW;
  const int time = tp - 15;
  const bool inb = (time >= 0) && (time < T_DIM);
  uint32_t off[4];
  #pragma unroll
  for (int b = 0; b < 4; ++b){
    float xv = inb ? x[(b * C_DIM + c) * T_DIM + time] : 0.0f;
    float q = rintf(xv * 128.0f);
    q = fminf(fmaxf(q, -128.0f), 128.0f);
    off[b] = (uint32_t)(((int)q + 128) * ROWB);      // LDS byte offset
  }
  wsq[m] = make_uint2(off[0] | (off[1] << 16), off[2] | (off[3] << 16));
}

// ------- pre-pass 2: transpose r to (c, k, is) float4 -----------------------
__global__ __launch_bounds__(256) void r_prepass(
    const float* __restrict__ r, float4* __restrict__ rT)
{
  const int m = blockIdx.x * 256 + threadIdx.x;      // over C_DIM*KW
  if (m >= C_DIM * KW) return;
  const int c = m / KW;
  const int k = m - c * KW;
  float4 v;
  v.x = r[(0 * C_DIM + c) * KW + k];
  v.y = r[(1 * C_DIM + c) * KW + k];
  v.z = r[(2 * C_DIM + c) * KW + k];
  v.w = r[(3 * C_DIM + c) * KW + k];
  rT[m] = v;
}

// ---------------- main kernel ----------------------------------------------
template<bool USE_WS>
__global__ __launch_bounds__(TPB) void memristor_main(
    const float* __restrict__ x,
    const float* __restrict__ poly_low,   // (2,2,7)
    const float* __restrict__ poly_high,  // (2,2,6)
    const float* __restrict__ r,          // (2,2,C,K)
    const float* __restrict__ bias,
    const uint2* __restrict__ wsq,        // (C, WSROW) packed u16 byte-offs x4
    const float4* __restrict__ rT,        // (C, K) -> (r0,r1,r2,r3)
    float* __restrict__ out,              // (B,C,TOUT)
    uint32_t nk0a, uint32_t nk0b, uint32_t nk1a, uint32_t nk1b,
    uint32_t nk2a, uint32_t nk2b, uint32_t nk3a, uint32_t nk3b)
{
  // row = 12 floats: [lo0,lo1,d0,d1, lo2,lo3,d2,d3, sj*sqrt2, pad x3]
  __shared__ __align__(16) float lut[257 * 12];

  const int tid = threadIdx.x;

  for (int qi = tid; qi < 257; qi += TPB){
    const float q = (float)(qi - 128);
    const float w = (q * 0.0078125f) * 0.6f;
    float lov[4], div[4];
    #pragma unroll
    for (int is = 0; is < 4; ++is){
      const float* pl = poly_low  + is * 7;
      const float* ph = poly_high + is * 6;
      float lo = pl[6];
      lo = fmaf(lo, w, pl[5]); lo = fmaf(lo, w, pl[4]); lo = fmaf(lo, w, pl[3]);
      lo = fmaf(lo, w, pl[2]); lo = fmaf(lo, w, pl[1]); lo = fmaf(lo, w, pl[0]);
      float hi = ph[5];
      hi = fmaf(hi, w, ph[4]); hi = fmaf(hi, w, ph[3]); hi = fmaf(hi, w, ph[2]);
      hi = fmaf(hi, w, ph[1]); hi = fmaf(hi, w, ph[0]);
      lov[is] = lo; div[is] = hi - lo;
    }
    lut[qi*12 + 0] = lov[0]; lut[qi*12 + 1] = lov[1];
    lut[qi*12 + 2] = div[0]; lut[qi*12 + 3] = div[1];
    lut[qi*12 + 4] = lov[2]; lut[qi*12 + 5] = lov[3];
    lut[qi*12 + 6] = div[2]; lut[qi*12 + 7] = div[3];
    const float jf = fmaf(1.6567788e-28f,
                          __builtin_amdgcn_rcpf(fabsf(w) + 1e-12f),
                          5.4365637e-08f);
    lut[qi*12 + 8] = __builtin_amdgcn_sqrtf(jf) * 1.41421356f; // sqrt2 folded
  }
  __syncthreads();

  // 4 lanes per (c,t): lane l covers k in [8l, min(8l+8, 31))
  const int l   = tid & 3;
  const int p   = tid >> 2;
  const int gid = blockIdx.x * PPB + p;     // exact: grid*PPB == C*TOUT
  const int c   = gid / TOUT;
  const int t   = gid - c * TOUT;
  const int k0  = l * 8;
  const int kn  = (l == 3) ? 7 : 8;

  const uint32_t ka[4] = {nk0a, nk1a, nk2a, nk3a};
  const uint32_t kb[4] = {nk0b, nk1b, nk2b, nk3b};
  const uint32_t jbase = (uint32_t)((t * C_DIM + c) * KW) + (uint32_t)k0;

  const uint2*  wp = USE_WS ? (wsq + c * WSROW + t + k0) : nullptr;
  const float4* rp = USE_WS ? (rT + c * KW + k0) : nullptr;

  f2 acc01[4], acc23[4];                    // [b], packed over is-pairs
  #pragma unroll
  for (int b = 0; b < 4; ++b){ acc01[b] = (f2)(0.0f); acc23[b] = (f2)(0.0f); }

  for (int kk = 0; kk < kn; ++kk){
    // ---- per-k loads (L2-resident, inline — no register arrays) ----
    uint32_t off0, off1, off2, off3;
    f2 rr01, rr23;
    if (USE_WS){
      const uint2  ld = wp[kk];
      const float4 rv = rp[kk];
      off0 = ld.x & 0xFFFFu; off1 = ld.x >> 16;
      off2 = ld.y & 0xFFFFu; off3 = ld.y >> 16;
      rr01 = (f2){rv.x, rv.y};
      rr23 = (f2){rv.z, rv.w};
    } else {
      const int k = k0 + kk;
      const int time = t + k - 15;
      const bool inb = (time >= 0) && (time < T_DIM);
      uint32_t off[4];
      #pragma unroll
      for (int b = 0; b < 4; ++b){
        float xv = inb ? x[(b * C_DIM + c) * T_DIM + time] : 0.0f;
        float q = rintf(xv * 128.0f);
        q = fminf(fmaxf(q, -128.0f), 128.0f);
        off[b] = (uint32_t)(((int)q + 128) * ROWB);
      }
      off0 = off[0]; off1 = off[1]; off2 = off[2]; off3 = off[3];
      rr01 = (f2){ r[(0 * C_DIM + c) * KW + k], r[(1 * C_DIM + c) * KW + k] };
      rr23 = (f2){ r[(2 * C_DIM + c) * KW + k], r[(3 * C_DIM + c) * KW + k] };
    }

    uint32_t bits[4];
    threefry_xor4(ka, kb, jbase + (uint32_t)kk, bits);

    // ---- packed u -> x, (1-x)(1+x) (math identical to validated R6) ----
    const f2 u01 = { __uint_as_float((bits[0] >> 9) | 0x3f800000u),
                     __uint_as_float((bits[1] >> 9) | 0x3f800000u) };
    const f2 u23 = { __uint_as_float((bits[2] >> 9) | 0x3f800000u),
                     __uint_as_float((bits[3] >> 9) | 0x3f800000u) };
    const float LO = -0.99999994f;
    const f2 u1_01 = u01 - 1.0f, u1_23 = u23 - 1.0f;
    const f2 x01 = u1_01 * 2.0f + LO;
    const f2 x23 = u1_23 * 2.0f + LO;
    const f2 a01 = u1_01 * (-2.0f) + 1.99999994f;   // 1-x
    const f2 a23 = u1_23 * (-2.0f) + 1.99999994f;
    const f2 b01 = u1_01 * 2.0f + 5.9604645e-8f;    // 1+x
    const f2 b23 = u1_23 * 2.0f + 5.9604645e-8f;
    const f2 pr01 = a01 * b01, pr23 = a23 * b23;

    // L = log2(pr); poly arg t = fma(L, -ln2, -2.5)
    const f2 L01 = { __builtin_amdgcn_logf(pr01.x),
                     __builtin_amdgcn_logf(pr01.y) };
    const f2 L23 = { __builtin_amdgcn_logf(pr23.x),
                     __builtin_amdgcn_logf(pr23.y) };
    const f2 t01 = L01 * (-0.69314718f) + (-2.5f);
    const f2 t23 = L23 * (-0.69314718f) + (-2.5f);

    f2 p01 = (f2)(2.81022636e-08f), p23 = (f2)(2.81022636e-08f);
    p01 = p01*t01 + 3.43273939e-07f;  p23 = p23*t23 + 3.43273939e-07f;
    p01 = p01*t01 + -3.5233877e-06f;  p23 = p23*t23 + -3.5233877e-06f;
    p01 = p01*t01 + -4.39150654e-06f; p23 = p23*t23 + -4.39150654e-06f;
    p01 = p01*t01 + 0.00021858087f;   p23 = p23*t23 + 0.00021858087f;
    p01 = p01*t01 + -0.00125372503f;  p23 = p23*t23 + -0.00125372503f;
    p01 = p01*t01 + -0.00417768164f;  p23 = p23*t23 + -0.00417768164f;
    p01 = p01*t01 + 0.246640727f;     p23 = p23*t23 + 0.246640727f;
    p01 = p01*t01 + 1.50140941f;      p23 = p23*t23 + 1.50140941f;

    // rare tail fixups: w >= 5  <=>  L <= -5/ln2
    const float LTH = -7.2134752f;
    if (L01.x <= LTH) p01.x = erfinv_hi(L01.x * -0.69314718f);
    if (L01.y <= LTH) p01.y = erfinv_hi(L01.y * -0.69314718f);
    if (L23.x <= LTH) p23.x = erfinv_hi(L23.x * -0.69314718f);
    if (L23.y <= LTH) p23.y = erfinv_hi(L23.y * -0.69314718f);

    const f2 noise01 = p01 * x01;     // sqrt2 folded into LUT sj
    const f2 noise23 = p23 * x23;

    #pragma unroll
    for (int b = 0; b < 4; ++b){
      const uint32_t off = (b == 0) ? off0 : (b == 1) ? off1 : (b == 2) ? off2 : off3;
      const float* row = (const float*)((const char*)lut + off);
      const float4 A  = *(const float4*)(row);      // lo0,lo1,d0,d1
      const float4 Bv = *(const float4*)(row + 4);  // lo2,lo3,d2,d3
      const float sj  = row[8];
      const f2 lo01 = {A.x, A.y},  d01 = {A.z, A.w};
      const f2 lo23 = {Bv.x, Bv.y}, d23 = {Bv.z, Bv.w};
      const f2 raw01 = d01 * rr01 + lo01;           // pk_fma
      const f2 raw23 = d23 * rr23 + lo23;
      const f2 s01 = { __builtin_amdgcn_sqrtf(fabsf(raw01.x)),
                       __builtin_amdgcn_sqrtf(fabsf(raw01.y)) };
      const f2 s23 = { __builtin_amdgcn_sqrtf(fabsf(raw23.x)),
                       __builtin_amdgcn_sqrtf(fabsf(raw23.y)) };
      const f2 nsj01 = noise01 * sj;
      const f2 nsj23 = noise23 * sj;
      acc01[b] = nsj01 * s01 + (acc01[b] + raw01);
      acc23[b] = nsj23 * s23 + (acc23[b] + raw23);
    }
  }

  // quad butterfly combine: every lane ends with full sums
  const float bv = bias[c];
  #pragma unroll
  for (int b = 0; b < 4; ++b){
    f2 t01 = acc01[b], t23 = acc23[b];
    t01.x += __shfl_xor(t01.x, 1); t01.x += __shfl_xor(t01.x, 2);
    t01.y += __shfl_xor(t01.y, 1); t01.y += __shfl_xor(t01.y, 2);
    t23.x += __shfl_xor(t23.x, 1); t23.x += __shfl_xor(t23.x, 2);
    t23.y += __shfl_xor(t23.y, 1); t23.y += __shfl_xor(t23.y, 2);
    acc01[b] = t01; acc23[b] = t23;
  }

  if (l == 0){
    #pragma unroll
    for (int b = 0; b < 4; ++b){
      float oo = 0.0f;
      {
        const float pair = acc01[b].x - acc01[b].y;   // i=0, weight 2
        float q = rintf((pair * 8020.0f) * 256.0f);
        q = fminf(fmaxf(q, -131072.0f), 131072.0f);
        oo += (q * 0.00390625f) * 2.0f;
      }
      {
        const float pair = acc23[b].x - acc23[b].y;   // i=1, weight 1
        float q = rintf((pair * 8020.0f) * 256.0f);
        q = fminf(fmaxf(q, -131072.0f), 131072.0f);
        oo += (q * 0.00390625f);
      }
      out[(b * C_DIM + c) * TOUT + t] = oo + bv;
    }
  }
}

extern "C" void kernel_launch(void* const* d_in, const int* in_sizes, int n_in,
                              void* d_out, int out_size, void* d_ws, size_t ws_size,
                              hipStream_t stream) {
  const float* x         = (const float*)d_in[0];
  const float* poly_low  = (const float*)d_in[1];
  const float* poly_high = (const float*)d_in[2];
  const float* r         = (const float*)d_in[3];
  const float* bias      = (const float*)d_in[4];
  float* out             = (float*)d_out;

  // key chain: key = jax.random.key(42); 4x (key, nk) = split(key)
  uint32_t ck0 = 0u, ck1 = 42u;
  uint32_t nk[4][2];
  for (int n = 0; n < 4; ++n){
    uint32_t a0, a1, b0, b1;
    h_threefry2x32(ck0, ck1, 0u, 0u, &a0, &a1);  // new key
    h_threefry2x32(ck0, ck1, 0u, 1u, &b0, &b1);  // nk
    nk[n][0] = b0; nk[n][1] = b1;
    ck0 = a0; ck1 = a1;
  }

  const int nblocks = (C_DIM * TOUT) / PPB;      // 3200, exact

  if (ws_size >= (size_t)WS_NEEDED){
    uint2*  wsq = (uint2*)d_ws;
    float4* rT  = (float4*)((char*)d_ws + RT_OFF);
    hipLaunchKernelGGL(dac_prepass, dim3((C_DIM * WSROW) / 256), dim3(256),
                       0, stream, x, wsq);
    hipLaunchKernelGGL(r_prepass, dim3((C_DIM * KW + 255) / 256), dim3(256),
                       0, stream, r, rT);
    hipLaunchKernelGGL((memristor_main<true>), dim3(nblocks), dim3(TPB), 0, stream,
                       x, poly_low, poly_high, r, bias, wsq, rT, out,
                       nk[0][0], nk[0][1], nk[1][0], nk[1][1],
                       nk[2][0], nk[2][1], nk[3][0], nk[3][1]);
  } else {
    hipLaunchKernelGGL((memristor_main<false>), dim3(nblocks), dim3(TPB), 0, stream,
                       x, poly_low, poly_high, r, bias,
                       (const uint2*)nullptr, (const float4*)nullptr, out,
                       nk[0][0], nk[0][1], nk[1][0], nk[1][1],
                       nk[2][0], nk[2][1], nk[3][0], nk[3][1]);
  }
}

// Round 9
// 103.083 us; speedup vs baseline: 2.3957x; 1.0185x over previous
//
#include <hip/hip_runtime.h>
#include <cstdint>

#define C_DIM 512
#define T_DIM 400
#define KW 31
#define TOUT 400
#define WSROW 432        // padded time index t+k in [0,430] -> 432
#define TPB 256
#define PPB 64           // (c,t) pairs per block; 4 k-split lanes each
#define ROWB 48          // LUT row stride in bytes (12 floats; 8 used, 16B-aligned)

#define WSQ_BYTES (C_DIM * WSROW * 8)            // 1,769,472
#define RT_OFF    WSQ_BYTES
#define RT_BYTES  (C_DIM * KW * 16)              // 253,952
#define WS_NEEDED (WSQ_BYTES + RT_BYTES)

// sigma = sqrt(johnson + shot); johnson/shot <= 3e-9 (KJ/(KS*|w|)) -> sigma
// = sqrt(2*E*BW)*sqrt(|raw|) to 9 digits. Fold sqrt2 (from jax normal) and
// sqrt(KS) into the x-transform constants:
//   C  = sqrt(2) * sqrt(5.4365637e-08) = 3.2974425e-4
#define TWO_C  6.5948850e-4f
#define LO_C  -3.2974423e-4f            // (-0.99999994) * C

typedef float f2 __attribute__((ext_vector_type(2)));

// ---------------- host threefry2x32 (key-chain computation, pure CPU) --------
static inline uint32_t h_rotl32(uint32_t x, int d){ return (x<<d)|(x>>(32-d)); }

static void h_threefry2x32(uint32_t k0, uint32_t k1, uint32_t x0, uint32_t x1,
                           uint32_t* o0, uint32_t* o1){
  uint32_t ks2 = k0 ^ k1 ^ 0x1BD11BDAu;
  uint32_t ks[3] = {k0, k1, ks2};
  const int rotA[4] = {13,15,26,6};
  const int rotB[4] = {17,29,16,24};
  uint32_t v0 = x0 + k0, v1 = x1 + k1;
  for (int r = 0; r < 5; ++r){
    const int* rot = (r & 1) ? rotB : rotA;
    for (int q = 0; q < 4; ++q){
      v0 += v1; v1 = h_rotl32(v1, rot[q]); v1 ^= v0;
    }
    v0 += ks[(r+1)%3];
    v1 += ks[(r+2)%3] + (uint32_t)(r+1);
  }
  *o0 = v0; *o1 = v1;
}

// ---------------- device threefry, 4 independent streams in lockstep --------
template<int R>
__device__ __forceinline__ void tfr4(uint32_t v0[4], uint32_t v1[4]){
  #pragma unroll
  for (int n = 0; n < 4; ++n){
    v0[n] += v1[n];
    v1[n] = (v1[n] << R) | (v1[n] >> (32 - R));   // -> v_alignbit_b32
    v1[n] ^= v0[n];
  }
}

__device__ __forceinline__ void tfinj4(uint32_t v0[4], uint32_t v1[4],
                                       const uint32_t a[4], const uint32_t b[4],
                                       uint32_t cadd){
  #pragma unroll
  for (int n = 0; n < 4; ++n){ v0[n] += a[n]; v1[n] += b[n] + cadd; }
}

__device__ __forceinline__ void threefry_xor4(const uint32_t ka[4], const uint32_t kb[4],
                                              uint32_t j, uint32_t out[4]){
  uint32_t ks2[4], v0[4], v1[4];
  #pragma unroll
  for (int n = 0; n < 4; ++n){
    ks2[n] = ka[n] ^ kb[n] ^ 0x1BD11BDAu;
    v0[n] = ka[n];            // x0 = 0
    v1[n] = j + kb[n];        // x1 = j
  }
  tfr4<13>(v0,v1); tfr4<15>(v0,v1); tfr4<26>(v0,v1); tfr4<6>(v0,v1);
  tfinj4(v0,v1,kb,ks2,1u);
  tfr4<17>(v0,v1); tfr4<29>(v0,v1); tfr4<16>(v0,v1); tfr4<24>(v0,v1);
  tfinj4(v0,v1,ks2,ka,2u);
  tfr4<13>(v0,v1); tfr4<15>(v0,v1); tfr4<26>(v0,v1); tfr4<6>(v0,v1);
  tfinj4(v0,v1,ka,kb,3u);
  tfr4<17>(v0,v1); tfr4<29>(v0,v1); tfr4<16>(v0,v1); tfr4<24>(v0,v1);
  tfinj4(v0,v1,kb,ks2,4u);
  tfr4<13>(v0,v1); tfr4<15>(v0,v1); tfr4<26>(v0,v1); tfr4<6>(v0,v1);
  tfinj4(v0,v1,ks2,ka,5u);
  #pragma unroll
  for (int n = 0; n < 4; ++n) out[n] = v0[n] ^ v1[n];
}

// high-branch (rare) scalar erfinv tail: returns p such that erfinv = p*x
__device__ __forceinline__ float erfinv_hi(float w){
  float ws = __builtin_amdgcn_sqrtf(w) - 3.0f;
  float p =             -0.000200214257f;
  p = fmaf(p, ws,   0.000100950558f);
  p = fmaf(p, ws,   0.00134934322f);
  p = fmaf(p, ws,  -0.00367342844f);
  p = fmaf(p, ws,   0.00573950773f);
  p = fmaf(p, ws,  -0.0076224613f);
  p = fmaf(p, ws,   0.00943887047f);
  p = fmaf(p, ws,   1.00167406f);
  p = fmaf(p, ws,   2.83297682f);
  return p;
}

// ------- pre-pass 1: DAC-quantize x once per (c,time), store LDS byte offs --
__global__ __launch_bounds__(256) void dac_prepass(
    const float* __restrict__ x, uint2* __restrict__ wsq)
{
  const int m = blockIdx.x * 256 + threadIdx.x;      // exact over C_DIM*WSROW
  const int c  = m / WSROW;
  const int tp = m - c * WSROW;
  const int time = tp - 15;
  const bool inb = (time >= 0) && (time < T_DIM);
  uint32_t off[4];
  #pragma unroll
  for (int b = 0; b < 4; ++b){
    float xv = inb ? x[(b * C_DIM + c) * T_DIM + time] : 0.0f;
    float q = rintf(xv * 128.0f);
    q = fminf(fmaxf(q, -128.0f), 128.0f);
    off[b] = (uint32_t)(((int)q + 128) * ROWB);      // LDS byte offset
  }
  wsq[m] = make_uint2(off[0] | (off[1] << 16), off[2] | (off[3] << 16));
}

// ------- pre-pass 2: transpose r to (c, k, is) float4 -----------------------
__global__ __launch_bounds__(256) void r_prepass(
    const float* __restrict__ r, float4* __restrict__ rT)
{
  const int m = blockIdx.x * 256 + threadIdx.x;      // over C_DIM*KW
  if (m >= C_DIM * KW) return;
  const int c = m / KW;
  const int k = m - c * KW;
  float4 v;
  v.x = r[(0 * C_DIM + c) * KW + k];
  v.y = r[(1 * C_DIM + c) * KW + k];
  v.z = r[(2 * C_DIM + c) * KW + k];
  v.w = r[(3 * C_DIM + c) * KW + k];
  rT[m] = v;
}

// ---------------- main kernel ----------------------------------------------
template<bool USE_WS>
__global__ __launch_bounds__(TPB) void memristor_main(
    const float* __restrict__ x,
    const float* __restrict__ poly_low,   // (2,2,7)
    const float* __restrict__ poly_high,  // (2,2,6)
    const float* __restrict__ r,          // (2,2,C,K)
    const float* __restrict__ bias,
    const uint2* __restrict__ wsq,        // (C, WSROW) packed u16 byte-offs x4
    const float4* __restrict__ rT,        // (C, K) -> (r0,r1,r2,r3)
    float* __restrict__ out,              // (B,C,TOUT)
    uint32_t nk0a, uint32_t nk0b, uint32_t nk1a, uint32_t nk1b,
    uint32_t nk2a, uint32_t nk2b, uint32_t nk3a, uint32_t nk3b)
{
  // row = 12 floats (48B stride, 16B aligned): [lo0,lo1,d0,d1, lo2,lo3,d2,d3]
  __shared__ __align__(16) float lut[257 * 12];
  __shared__ __align__(16) float4 rbuf[2][KW];   // block-local rT rows (<=2 c's)

  const int tid = threadIdx.x;
  const int c_first = (blockIdx.x * PPB) / TOUT; // c of the block's first pair

  for (int qi = tid; qi < 257; qi += TPB){
    const float q = (float)(qi - 128);
    const float w = (q * 0.0078125f) * 0.6f;
    float lov[4], div[4];
    #pragma unroll
    for (int is = 0; is < 4; ++is){
      const float* pl = poly_low  + is * 7;
      const float* ph = poly_high + is * 6;
      float lo = pl[6];
      lo = fmaf(lo, w, pl[5]); lo = fmaf(lo, w, pl[4]); lo = fmaf(lo, w, pl[3]);
      lo = fmaf(lo, w, pl[2]); lo = fmaf(lo, w, pl[1]); lo = fmaf(lo, w, pl[0]);
      float hi = ph[5];
      hi = fmaf(hi, w, ph[4]); hi = fmaf(hi, w, ph[3]); hi = fmaf(hi, w, ph[2]);
      hi = fmaf(hi, w, ph[1]); hi = fmaf(hi, w, ph[0]);
      lov[is] = lo; div[is] = hi - lo;
    }
    lut[qi*12 + 0] = lov[0]; lut[qi*12 + 1] = lov[1];
    lut[qi*12 + 2] = div[0]; lut[qi*12 + 3] = div[1];
    lut[qi*12 + 4] = lov[2]; lut[qi*12 + 5] = lov[3];
    lut[qi*12 + 6] = div[2]; lut[qi*12 + 7] = div[3];
  }
  if (USE_WS && tid < 2 * KW){
    const int which = tid / KW, k = tid - which * KW;
    const int cc = c_first + which;
    if (cc < C_DIM) rbuf[which][k] = rT[cc * KW + k];
  }
  __syncthreads();

  // 4 lanes per (c,t): lane l covers k in [8l, min(8l+8, 31))
  const int l   = tid & 3;
  const int p   = tid >> 2;
  const int gid = blockIdx.x * PPB + p;     // exact: grid*PPB == C*TOUT
  const int c   = gid / TOUT;
  const int t   = gid - c * TOUT;
  const int k0  = l * 8;
  const int kn  = (l == 3) ? 7 : 8;
  const int cw  = c - c_first;              // 0 or 1

  const uint32_t ka[4] = {nk0a, nk1a, nk2a, nk3a};
  const uint32_t kb[4] = {nk0b, nk1b, nk2b, nk3b};
  const uint32_t jbase = (uint32_t)((t * C_DIM + c) * KW) + (uint32_t)k0;

  const uint2* wp = USE_WS ? (wsq + c * WSROW + t + k0) : nullptr;

  f2 acc01[4], acc23[4];                    // [b], packed over is-pairs
  #pragma unroll
  for (int b = 0; b < 4; ++b){ acc01[b] = (f2)(0.0f); acc23[b] = (f2)(0.0f); }

  for (int kk = 0; kk < kn; ++kk){
    // ---- per-k loads ----
    uint32_t off0, off1, off2, off3;
    f2 rr01, rr23;
    if (USE_WS){
      const uint2  ld = wp[kk];
      const float4 rv = rbuf[cw][k0 + kk];
      off0 = ld.x & 0xFFFFu; off1 = ld.x >> 16;
      off2 = ld.y & 0xFFFFu; off3 = ld.y >> 16;
      rr01 = (f2){rv.x, rv.y};
      rr23 = (f2){rv.z, rv.w};
    } else {
      const int k = k0 + kk;
      const int time = t + k - 15;
      const bool inb = (time >= 0) && (time < T_DIM);
      uint32_t off[4];
      #pragma unroll
      for (int b = 0; b < 4; ++b){
        float xv = inb ? x[(b * C_DIM + c) * T_DIM + time] : 0.0f;
        float q = rintf(xv * 128.0f);
        q = fminf(fmaxf(q, -128.0f), 128.0f);
        off[b] = (uint32_t)(((int)q + 128) * ROWB);
      }
      off0 = off[0]; off1 = off[1]; off2 = off[2]; off3 = off[3];
      rr01 = (f2){ r[(0 * C_DIM + c) * KW + k], r[(1 * C_DIM + c) * KW + k] };
      rr23 = (f2){ r[(2 * C_DIM + c) * KW + k], r[(3 * C_DIM + c) * KW + k] };
    }

    uint32_t bits[4];
    threefry_xor4(ka, kb, jbase + (uint32_t)kk, bits);

    // ---- packed u -> x (pre-scaled by C), (1-x)(1+x) ----
    const f2 u01 = { __uint_as_float((bits[0] >> 9) | 0x3f800000u),
                     __uint_as_float((bits[1] >> 9) | 0x3f800000u) };
    const f2 u23 = { __uint_as_float((bits[2] >> 9) | 0x3f800000u),
                     __uint_as_float((bits[3] >> 9) | 0x3f800000u) };
    const f2 u1_01 = u01 - 1.0f, u1_23 = u23 - 1.0f;
    const f2 x01 = u1_01 * TWO_C + LO_C;            // x * C (sigma-folded)
    const f2 x23 = u1_23 * TWO_C + LO_C;
    const f2 a01 = u1_01 * (-2.0f) + 1.99999994f;   // 1-x (unscaled)
    const f2 a23 = u1_23 * (-2.0f) + 1.99999994f;
    const f2 b01 = u1_01 * 2.0f + 5.9604645e-8f;    // 1+x
    const f2 b23 = u1_23 * 2.0f + 5.9604645e-8f;
    const f2 pr01 = a01 * b01, pr23 = a23 * b23;

    // L = log2(pr); poly arg t = fma(L, -ln2, -2.5)
    const f2 L01 = { __builtin_amdgcn_logf(pr01.x),
                     __builtin_amdgcn_logf(pr01.y) };
    const f2 L23 = { __builtin_amdgcn_logf(pr23.x),
                     __builtin_amdgcn_logf(pr23.y) };
    const f2 t01 = L01 * (-0.69314718f) + (-2.5f);
    const f2 t23 = L23 * (-0.69314718f) + (-2.5f);

    f2 p01 = (f2)(2.81022636e-08f), p23 = (f2)(2.81022636e-08f);
    p01 = p01*t01 + 3.43273939e-07f;  p23 = p23*t23 + 3.43273939e-07f;
    p01 = p01*t01 + -3.5233877e-06f;  p23 = p23*t23 + -3.5233877e-06f;
    p01 = p01*t01 + -4.39150654e-06f; p23 = p23*t23 + -4.39150654e-06f;
    p01 = p01*t01 + 0.00021858087f;   p23 = p23*t23 + 0.00021858087f;
    p01 = p01*t01 + -0.00125372503f;  p23 = p23*t23 + -0.00125372503f;
    p01 = p01*t01 + -0.00417768164f;  p23 = p23*t23 + -0.00417768164f;
    p01 = p01*t01 + 0.246640727f;     p23 = p23*t23 + 0.246640727f;
    p01 = p01*t01 + 1.50140941f;      p23 = p23*t23 + 1.50140941f;

    // rare tail fixups: w >= 5  <=>  L <= -5/ln2
    const float LTH = -7.2134752f;
    if (L01.x <= LTH) p01.x = erfinv_hi(L01.x * -0.69314718f);
    if (L01.y <= LTH) p01.y = erfinv_hi(L01.y * -0.69314718f);
    if (L23.x <= LTH) p23.x = erfinv_hi(L23.x * -0.69314718f);
    if (L23.y <= LTH) p23.y = erfinv_hi(L23.y * -0.69314718f);

    const f2 noise01 = p01 * x01;     // = normal_sample * sqrt2 * sqrt(KS)
    const f2 noise23 = p23 * x23;

    #pragma unroll
    for (int b = 0; b < 4; ++b){
      const uint32_t off = (b == 0) ? off0 : (b == 1) ? off1 : (b == 2) ? off2 : off3;
      const float* row = (const float*)((const char*)lut + off);
      const float4 A  = *(const float4*)(row);      // lo0,lo1,d0,d1
      const float4 Bv = *(const float4*)(row + 4);  // lo2,lo3,d2,d3
      const f2 lo01 = {A.x, A.y},  d01 = {A.z, A.w};
      const f2 lo23 = {Bv.x, Bv.y}, d23 = {Bv.z, Bv.w};
      const f2 raw01 = d01 * rr01 + lo01;           // pk_fma
      const f2 raw23 = d23 * rr23 + lo23;
      const f2 s01 = { __builtin_amdgcn_sqrtf(fabsf(raw01.x)),
                       __builtin_amdgcn_sqrtf(fabsf(raw01.y)) };
      const f2 s23 = { __builtin_amdgcn_sqrtf(fabsf(raw23.x)),
                       __builtin_amdgcn_sqrtf(fabsf(raw23.y)) };
      acc01[b] = noise01 * s01 + (acc01[b] + raw01);
      acc23[b] = noise23 * s23 + (acc23[b] + raw23);
    }
  }

  // quad butterfly combine: every lane ends with full sums
  const float bv = bias[c];
  #pragma unroll
  for (int b = 0; b < 4; ++b){
    f2 t01 = acc01[b], t23 = acc23[b];
    t01.x += __shfl_xor(t01.x, 1); t01.x += __shfl_xor(t01.x, 2);
    t01.y += __shfl_xor(t01.y, 1); t01.y += __shfl_xor(t01.y, 2);
    t23.x += __shfl_xor(t23.x, 1); t23.x += __shfl_xor(t23.x, 2);
    t23.y += __shfl_xor(t23.y, 1); t23.y += __shfl_xor(t23.y, 2);
    acc01[b] = t01; acc23[b] = t23;
  }

  if (l == 0){
    #pragma unroll
    for (int b = 0; b < 4; ++b){
      float oo = 0.0f;
      {
        const float pair = acc01[b].x - acc01[b].y;   // i=0, weight 2
        float q = rintf((pair * 8020.0f) * 256.0f);
        q = fminf(fmaxf(q, -131072.0f), 131072.0f);
        oo += (q * 0.00390625f) * 2.0f;
      }
      {
        const float pair = acc23[b].x - acc23[b].y;   // i=1, weight 1
        float q = rintf((pair * 8020.0f) * 256.0f);
        q = fminf(fmaxf(q, -131072.0f), 131072.0f);
        oo += (q * 0.00390625f);
      }
      out[(b * C_DIM + c) * TOUT + t] = oo + bv;
    }
  }
}

extern "C" void kernel_launch(void* const* d_in, const int* in_sizes, int n_in,
                              void* d_out, int out_size, void* d_ws, size_t ws_size,
                              hipStream_t stream) {
  const float* x         = (const float*)d_in[0];
  const float* poly_low  = (const float*)d_in[1];
  const float* poly_high = (const float*)d_in[2];
  const float* r         = (const float*)d_in[3];
  const float* bias      = (const float*)d_in[4];
  float* out             = (float*)d_out;

  // key chain: key = jax.random.key(42); 4x (key, nk) = split(key)
  uint32_t ck0 = 0u, ck1 = 42u;
  uint32_t nk[4][2];
  for (int n = 0; n < 4; ++n){
    uint32_t a0, a1, b0, b1;
    h_threefry2x32(ck0, ck1, 0u, 0u, &a0, &a1);  // new key
    h_threefry2x32(ck0, ck1, 0u, 1u, &b0, &b1);  // nk
    nk[n][0] = b0; nk[n][1] = b1;
    ck0 = a0; ck1 = a1;
  }

  const int nblocks = (C_DIM * TOUT) / PPB;      // 3200, exact

  if (ws_size >= (size_t)WS_NEEDED){
    uint2*  wsq = (uint2*)d_ws;
    float4* rT  = (float4*)((char*)d_ws + RT_OFF);
    hipLaunchKernelGGL(dac_prepass, dim3((C_DIM * WSROW) / 256), dim3(256),
                       0, stream, x, wsq);
    hipLaunchKernelGGL(r_prepass, dim3((C_DIM * KW + 255) / 256), dim3(256),
                       0, stream, r, rT);
    hipLaunchKernelGGL((memristor_main<true>), dim3(nblocks), dim3(TPB), 0, stream,
                       x, poly_low, poly_high, r, bias, wsq, rT, out,
                       nk[0][0], nk[0][1], nk[1][0], nk[1][1],
                       nk[2][0], nk[2][1], nk[3][0], nk[3][1]);
  } else {
    hipLaunchKernelGGL((memristor_main<false>), dim3(nblocks), dim3(TPB), 0, stream,
                       x, poly_low, poly_high, r, bias,
                       (const uint2*)nullptr, (const float4*)nullptr, out,
                       nk[0][0], nk[0][1], nk[1][0], nk[1][1],
                       nk[2][0], nk[2][1], nk[3][0], nk[3][1]);
  }
}

// Round 10
// 102.668 us; speedup vs baseline: 2.4054x; 1.0040x over previous
//
#include <hip/hip_runtime.h>
#include <cstdint>

#define C_DIM 512
#define T_DIM 400
#define KW 31
#define TOUT 400
#define WSROW 432        // padded time index t+k in [0,430] -> 432
#define TPB 256
#define PPB 64           // (c,t) pairs per block; 4 k-split lanes each
#define ROWB 48          // LUT row stride in bytes (12 floats; 8 used, 16B-aligned)
#define COPYB 12352      // second LUT copy byte offset: 257*48 + 16 (bank skew)

#define WSQ_BYTES (C_DIM * WSROW * 8)            // 1,769,472
#define RT_OFF    WSQ_BYTES
#define RT_BYTES  (C_DIM * KW * 16)              // 253,952
#define WS_NEEDED (WSQ_BYTES + RT_BYTES)

// sigma = sqrt(johnson + shot); johnson/shot <= 3e-9 -> sigma =
// sqrt(2*E*BW)*sqrt(|raw|) to 9 digits. sqrt2 (jax normal) and sqrt(KS)
// folded into the x-transform constants: C = sqrt(2*5.4365637e-08)
#define TWO_C  6.5948850e-4f
#define LO_C  -3.2974423e-4f            // (-0.99999994) * C

typedef float f2 __attribute__((ext_vector_type(2)));

// ---------------- host threefry2x32 (key-chain computation, pure CPU) --------
static inline uint32_t h_rotl32(uint32_t x, int d){ return (x<<d)|(x>>(32-d)); }

static void h_threefry2x32(uint32_t k0, uint32_t k1, uint32_t x0, uint32_t x1,
                           uint32_t* o0, uint32_t* o1){
  uint32_t ks2 = k0 ^ k1 ^ 0x1BD11BDAu;
  uint32_t ks[3] = {k0, k1, ks2};
  const int rotA[4] = {13,15,26,6};
  const int rotB[4] = {17,29,16,24};
  uint32_t v0 = x0 + k0, v1 = x1 + k1;
  for (int r = 0; r < 5; ++r){
    const int* rot = (r & 1) ? rotB : rotA;
    for (int q = 0; q < 4; ++q){
      v0 += v1; v1 = h_rotl32(v1, rot[q]); v1 ^= v0;
    }
    v0 += ks[(r+1)%3];
    v1 += ks[(r+2)%3] + (uint32_t)(r+1);
  }
  *o0 = v0; *o1 = v1;
}

// ---------------- device threefry, 4 independent streams in lockstep --------
template<int R>
__device__ __forceinline__ void tfr4(uint32_t v0[4], uint32_t v1[4]){
  #pragma unroll
  for (int n = 0; n < 4; ++n){
    v0[n] += v1[n];
    v1[n] = (v1[n] << R) | (v1[n] >> (32 - R));   // -> v_alignbit_b32
    v1[n] ^= v0[n];
  }
}

__device__ __forceinline__ void tfinj4(uint32_t v0[4], uint32_t v1[4],
                                       const uint32_t a[4], const uint32_t b[4],
                                       uint32_t cadd){
  #pragma unroll
  for (int n = 0; n < 4; ++n){ v0[n] += a[n]; v1[n] += b[n] + cadd; }
}

__device__ __forceinline__ void threefry_xor4(const uint32_t ka[4], const uint32_t kb[4],
                                              uint32_t j, uint32_t out[4]){
  uint32_t ks2[4], v0[4], v1[4];
  #pragma unroll
  for (int n = 0; n < 4; ++n){
    ks2[n] = ka[n] ^ kb[n] ^ 0x1BD11BDAu;
    v0[n] = ka[n];            // x0 = 0
    v1[n] = j + kb[n];        // x1 = j
  }
  tfr4<13>(v0,v1); tfr4<15>(v0,v1); tfr4<26>(v0,v1); tfr4<6>(v0,v1);
  tfinj4(v0,v1,kb,ks2,1u);
  tfr4<17>(v0,v1); tfr4<29>(v0,v1); tfr4<16>(v0,v1); tfr4<24>(v0,v1);
  tfinj4(v0,v1,ks2,ka,2u);
  tfr4<13>(v0,v1); tfr4<15>(v0,v1); tfr4<26>(v0,v1); tfr4<6>(v0,v1);
  tfinj4(v0,v1,ka,kb,3u);
  tfr4<17>(v0,v1); tfr4<29>(v0,v1); tfr4<16>(v0,v1); tfr4<24>(v0,v1);
  tfinj4(v0,v1,kb,ks2,4u);
  tfr4<13>(v0,v1); tfr4<15>(v0,v1); tfr4<26>(v0,v1); tfr4<6>(v0,v1);
  tfinj4(v0,v1,ks2,ka,5u);
  #pragma unroll
  for (int n = 0; n < 4; ++n) out[n] = v0[n] ^ v1[n];
}

// high-branch (rare) scalar erfinv tail: returns p such that erfinv = p*x
__device__ __forceinline__ float erfinv_hi(float w){
  float ws = __builtin_amdgcn_sqrtf(w) - 3.0f;
  float p =             -0.000200214257f;
  p = fmaf(p, ws,   0.000100950558f);
  p = fmaf(p, ws,   0.00134934322f);
  p = fmaf(p, ws,  -0.00367342844f);
  p = fmaf(p, ws,   0.00573950773f);
  p = fmaf(p, ws,  -0.0076224613f);
  p = fmaf(p, ws,   0.00943887047f);
  p = fmaf(p, ws,   1.00167406f);
  p = fmaf(p, ws,   2.83297682f);
  return p;
}

// ------- pre-pass 1: DAC-quantize x once per (c,time), store LDS byte offs --
__global__ __launch_bounds__(256) void dac_prepass(
    const float* __restrict__ x, uint2* __restrict__ wsq)
{
  const int m = blockIdx.x * 256 + threadIdx.x;      // exact over C_DIM*WSROW
  const int c  = m / WSROW;
  const int tp = m - c * WSROW;
  const int time = tp - 15;
  const bool inb = (time >= 0) && (time < T_DIM);
  uint32_t off[4];
  #pragma unroll
  for (int b = 0; b < 4; ++b){
    float xv = inb ? x[(b * C_DIM + c) * T_DIM + time] : 0.0f;
    float q = rintf(xv * 128.0f);
    q = fminf(fmaxf(q, -128.0f), 128.0f);
    off[b] = (uint32_t)(((int)q + 128) * ROWB);      // LDS byte offset
  }
  wsq[m] = make_uint2(off[0] | (off[1] << 16), off[2] | (off[3] << 16));
}

// ------- pre-pass 2: transpose r to (c, k, is) float4 -----------------------
__global__ __launch_bounds__(256) void r_prepass(
    const float* __restrict__ r, float4* __restrict__ rT)
{
  const int m = blockIdx.x * 256 + threadIdx.x;      // over C_DIM*KW
  if (m >= C_DIM * KW) return;
  const int c = m / KW;
  const int k = m - c * KW;
  float4 v;
  v.x = r[(0 * C_DIM + c) * KW + k];
  v.y = r[(1 * C_DIM + c) * KW + k];
  v.z = r[(2 * C_DIM + c) * KW + k];
  v.w = r[(3 * C_DIM + c) * KW + k];
  rT[m] = v;
}

// ---------------- main kernel ----------------------------------------------
template<bool USE_WS>
__global__ __launch_bounds__(TPB) void memristor_main(
    const float* __restrict__ x,
    const float* __restrict__ poly_low,   // (2,2,7)
    const float* __restrict__ poly_high,  // (2,2,6)
    const float* __restrict__ r,          // (2,2,C,K)
    const float* __restrict__ bias,
    const uint2* __restrict__ wsq,        // (C, WSROW) packed u16 byte-offs x4
    const float4* __restrict__ rT,        // (C, K) -> (r0,r1,r2,r3)
    float* __restrict__ out,              // (B,C,TOUT)
    uint32_t nk0a, uint32_t nk0b, uint32_t nk1a, uint32_t nk1b,
    uint32_t nk2a, uint32_t nk2b, uint32_t nk3a, uint32_t nk3b)
{
  // Two skewed LUT copies (even lanes copy0, odd lanes copy1 at +COPYB
  // = 257*48 + 16 bytes: bank-group map shifts by 4 -> hotspots decorrelate).
  // row = 12 floats (48B stride): [lo0,lo1,d0,d1, lo2,lo3,d2,d3, pad x4]
  __shared__ __align__(16) float lut[(COPYB / 4) + 257 * 12];
  __shared__ __align__(16) float4 rbuf[2][KW];   // block-local rT rows (<=2 c's)

  const int tid = threadIdx.x;
  const int c_first = (blockIdx.x * PPB) / TOUT; // c of the block's first pair

  for (int qi = tid; qi < 257; qi += TPB){
    const float q = (float)(qi - 128);
    const float w = (q * 0.0078125f) * 0.6f;
    float lov[4], div[4];
    #pragma unroll
    for (int is = 0; is < 4; ++is){
      const float* pl = poly_low  + is * 7;
      const float* ph = poly_high + is * 6;
      float lo = pl[6];
      lo = fmaf(lo, w, pl[5]); lo = fmaf(lo, w, pl[4]); lo = fmaf(lo, w, pl[3]);
      lo = fmaf(lo, w, pl[2]); lo = fmaf(lo, w, pl[1]); lo = fmaf(lo, w, pl[0]);
      float hi = ph[5];
      hi = fmaf(hi, w, ph[4]); hi = fmaf(hi, w, ph[3]); hi = fmaf(hi, w, ph[2]);
      hi = fmaf(hi, w, ph[1]); hi = fmaf(hi, w, ph[0]);
      lov[is] = lo; div[is] = hi - lo;
    }
    float* r0 = lut + qi * 12;
    float* r1 = lut + (COPYB / 4) + qi * 12;
    r0[0] = lov[0]; r0[1] = lov[1]; r0[2] = div[0]; r0[3] = div[1];
    r0[4] = lov[2]; r0[5] = lov[3]; r0[6] = div[2]; r0[7] = div[3];
    r1[0] = lov[0]; r1[1] = lov[1]; r1[2] = div[0]; r1[3] = div[1];
    r1[4] = lov[2]; r1[5] = lov[3]; r1[6] = div[2]; r1[7] = div[3];
  }
  if (USE_WS && tid < 2 * KW){
    const int which = tid / KW, k = tid - which * KW;
    const int cc = c_first + which;
    if (cc < C_DIM) rbuf[which][k] = rT[cc * KW + k];
  }
  __syncthreads();

  // per-thread LUT base: lane parity selects the skewed copy (computed once)
  const char* lbase = (const char*)lut + (tid & 1) * COPYB;

  // 4 lanes per (c,t): lane l covers k in [8l, min(8l+8, 31))
  const int l   = tid & 3;
  const int p   = tid >> 2;
  const int gid = blockIdx.x * PPB + p;     // exact: grid*PPB == C*TOUT
  const int c   = gid / TOUT;
  const int t   = gid - c * TOUT;
  const int k0  = l * 8;
  const int kn  = (l == 3) ? 7 : 8;
  const int cw  = c - c_first;              // 0 or 1

  const uint32_t ka[4] = {nk0a, nk1a, nk2a, nk3a};
  const uint32_t kb[4] = {nk0b, nk1b, nk2b, nk3b};
  const uint32_t jbase = (uint32_t)((t * C_DIM + c) * KW) + (uint32_t)k0;

  const uint2* wp = USE_WS ? (wsq + c * WSROW + t + k0) : nullptr;

  f2 acc01[4], acc23[4];                    // [b], packed over is-pairs
  #pragma unroll
  for (int b = 0; b < 4; ++b){ acc01[b] = (f2)(0.0f); acc23[b] = (f2)(0.0f); }

  for (int kk = 0; kk < kn; ++kk){
    // ---- per-k loads ----
    uint32_t off0, off1, off2, off3;
    f2 rr01, rr23;
    if (USE_WS){
      const uint2  ld = wp[kk];
      const float4 rv = rbuf[cw][k0 + kk];
      off0 = ld.x & 0xFFFFu; off1 = ld.x >> 16;
      off2 = ld.y & 0xFFFFu; off3 = ld.y >> 16;
      rr01 = (f2){rv.x, rv.y};
      rr23 = (f2){rv.z, rv.w};
    } else {
      const int k = k0 + kk;
      const int time = t + k - 15;
      const bool inb = (time >= 0) && (time < T_DIM);
      uint32_t off[4];
      #pragma unroll
      for (int b = 0; b < 4; ++b){
        float xv = inb ? x[(b * C_DIM + c) * T_DIM + time] : 0.0f;
        float q = rintf(xv * 128.0f);
        q = fminf(fmaxf(q, -128.0f), 128.0f);
        off[b] = (uint32_t)(((int)q + 128) * ROWB);
      }
      off0 = off[0]; off1 = off[1]; off2 = off[2]; off3 = off[3];
      rr01 = (f2){ r[(0 * C_DIM + c) * KW + k], r[(1 * C_DIM + c) * KW + k] };
      rr23 = (f2){ r[(2 * C_DIM + c) * KW + k], r[(3 * C_DIM + c) * KW + k] };
    }

    uint32_t bits[4];
    threefry_xor4(ka, kb, jbase + (uint32_t)kk, bits);

    // ---- packed u -> x (pre-scaled by C), (1-x)(1+x) ----
    const f2 u01 = { __uint_as_float((bits[0] >> 9) | 0x3f800000u),
                     __uint_as_float((bits[1] >> 9) | 0x3f800000u) };
    const f2 u23 = { __uint_as_float((bits[2] >> 9) | 0x3f800000u),
                     __uint_as_float((bits[3] >> 9) | 0x3f800000u) };
    const f2 u1_01 = u01 - 1.0f, u1_23 = u23 - 1.0f;
    const f2 x01 = u1_01 * TWO_C + LO_C;            // x * C (sigma-folded)
    const f2 x23 = u1_23 * TWO_C + LO_C;
    const f2 a01 = u1_01 * (-2.0f) + 1.99999994f;   // 1-x (unscaled)
    const f2 a23 = u1_23 * (-2.0f) + 1.99999994f;
    const f2 b01 = u1_01 * 2.0f + 5.9604645e-8f;    // 1+x
    const f2 b23 = u1_23 * 2.0f + 5.9604645e-8f;
    const f2 pr01 = a01 * b01, pr23 = a23 * b23;

    // L = log2(pr); poly arg t = fma(L, -ln2, -2.5)
    const f2 L01 = { __builtin_amdgcn_logf(pr01.x),
                     __builtin_amdgcn_logf(pr01.y) };
    const f2 L23 = { __builtin_amdgcn_logf(pr23.x),
                     __builtin_amdgcn_logf(pr23.y) };
    const f2 t01 = L01 * (-0.69314718f) + (-2.5f);
    const f2 t23 = L23 * (-0.69314718f) + (-2.5f);

    f2 p01 = (f2)(2.81022636e-08f), p23 = (f2)(2.81022636e-08f);
    p01 = p01*t01 + 3.43273939e-07f;  p23 = p23*t23 + 3.43273939e-07f;
    p01 = p01*t01 + -3.5233877e-06f;  p23 = p23*t23 + -3.5233877e-06f;
    p01 = p01*t01 + -4.39150654e-06f; p23 = p23*t23 + -4.39150654e-06f;
    p01 = p01*t01 + 0.00021858087f;   p23 = p23*t23 + 0.00021858087f;
    p01 = p01*t01 + -0.00125372503f;  p23 = p23*t23 + -0.00125372503f;
    p01 = p01*t01 + -0.00417768164f;  p23 = p23*t23 + -0.00417768164f;
    p01 = p01*t01 + 0.246640727f;     p23 = p23*t23 + 0.246640727f;
    p01 = p01*t01 + 1.50140941f;      p23 = p23*t23 + 1.50140941f;

    // rare tail fixups: w >= 5  <=>  L <= -5/ln2
    const float LTH = -7.2134752f;
    if (L01.x <= LTH) p01.x = erfinv_hi(L01.x * -0.69314718f);
    if (L01.y <= LTH) p01.y = erfinv_hi(L01.y * -0.69314718f);
    if (L23.x <= LTH) p23.x = erfinv_hi(L23.x * -0.69314718f);
    if (L23.y <= LTH) p23.y = erfinv_hi(L23.y * -0.69314718f);

    const f2 noise01 = p01 * x01;     // = normal_sample * sqrt2 * sqrt(KS)
    const f2 noise23 = p23 * x23;

    #pragma unroll
    for (int b = 0; b < 4; ++b){
      const uint32_t off = (b == 0) ? off0 : (b == 1) ? off1 : (b == 2) ? off2 : off3;
      const float* row = (const float*)(lbase + off);
      const float4 A  = *(const float4*)(row);      // lo0,lo1,d0,d1
      const float4 Bv = *(const float4*)(row + 4);  // lo2,lo3,d2,d3
      const f2 lo01 = {A.x, A.y},  d01 = {A.z, A.w};
      const f2 lo23 = {Bv.x, Bv.y}, d23 = {Bv.z, Bv.w};
      const f2 raw01 = d01 * rr01 + lo01;           // pk_fma
      const f2 raw23 = d23 * rr23 + lo23;
      const f2 s01 = { __builtin_amdgcn_sqrtf(fabsf(raw01.x)),
                       __builtin_amdgcn_sqrtf(fabsf(raw01.y)) };
      const f2 s23 = { __builtin_amdgcn_sqrtf(fabsf(raw23.x)),
                       __builtin_amdgcn_sqrtf(fabsf(raw23.y)) };
      acc01[b] = noise01 * s01 + (acc01[b] + raw01);
      acc23[b] = noise23 * s23 + (acc23[b] + raw23);
    }
  }

  // quad butterfly combine: every lane ends with full sums
  const float bv = bias[c];
  #pragma unroll
  for (int b = 0; b < 4; ++b){
    f2 t01 = acc01[b], t23 = acc23[b];
    t01.x += __shfl_xor(t01.x, 1); t01.x += __shfl_xor(t01.x, 2);
    t01.y += __shfl_xor(t01.y, 1); t01.y += __shfl_xor(t01.y, 2);
    t23.x += __shfl_xor(t23.x, 1); t23.x += __shfl_xor(t23.x, 2);
    t23.y += __shfl_xor(t23.y, 1); t23.y += __shfl_xor(t23.y, 2);
    acc01[b] = t01; acc23[b] = t23;
  }

  if (l == 0){
    #pragma unroll
    for (int b = 0; b < 4; ++b){
      float oo = 0.0f;
      {
        const float pair = acc01[b].x - acc01[b].y;   // i=0, weight 2
        float q = rintf((pair * 8020.0f) * 256.0f);
        q = fminf(fmaxf(q, -131072.0f), 131072.0f);
        oo += (q * 0.00390625f) * 2.0f;
      }
      {
        const float pair = acc23[b].x - acc23[b].y;   // i=1, weight 1
        float q = rintf((pair * 8020.0f) * 256.0f);
        q = fminf(fmaxf(q, -131072.0f), 131072.0f);
        oo += (q * 0.00390625f);
      }
      out[(b * C_DIM + c) * TOUT + t] = oo + bv;
    }
  }
}

extern "C" void kernel_launch(void* const* d_in, const int* in_sizes, int n_in,
                              void* d_out, int out_size, void* d_ws, size_t ws_size,
                              hipStream_t stream) {
  const float* x         = (const float*)d_in[0];
  const float* poly_low  = (const float*)d_in[1];
  const float* poly_high = (const float*)d_in[2];
  const float* r         = (const float*)d_in[3];
  const float* bias      = (const float*)d_in[4];
  float* out             = (float*)d_out;

  // key chain: key = jax.random.key(42); 4x (key, nk) = split(key)
  uint32_t ck0 = 0u, ck1 = 42u;
  uint32_t nk[4][2];
  for (int n = 0; n < 4; ++n){
    uint32_t a0, a1, b0, b1;
    h_threefry2x32(ck0, ck1, 0u, 0u, &a0, &a1);  // new key
    h_threefry2x32(ck0, ck1, 0u, 1u, &b0, &b1);  // nk
    nk[n][0] = b0; nk[n][1] = b1;
    ck0 = a0; ck1 = a1;
  }

  const int nblocks = (C_DIM * TOUT) / PPB;      // 3200, exact

  if (ws_size >= (size_t)WS_NEEDED){
    uint2*  wsq = (uint2*)d_ws;
    float4* rT  = (float4*)((char*)d_ws + RT_OFF);
    hipLaunchKernelGGL(dac_prepass, dim3((C_DIM * WSROW) / 256), dim3(256),
                       0, stream, x, wsq);
    hipLaunchKernelGGL(r_prepass, dim3((C_DIM * KW + 255) / 256), dim3(256),
                       0, stream, r, rT);
    hipLaunchKernelGGL((memristor_main<true>), dim3(nblocks), dim3(TPB), 0, stream,
                       x, poly_low, poly_high, r, bias, wsq, rT, out,
                       nk[0][0], nk[0][1], nk[1][0], nk[1][1],
                       nk[2][0], nk[2][1], nk[3][0], nk[3][1]);
  } else {
    hipLaunchKernelGGL((memristor_main<false>), dim3(nblocks), dim3(TPB), 0, stream,
                       x, poly_low, poly_high, r, bias,
                       (const uint2*)nullptr, (const float4*)nullptr, out,
                       nk[0][0], nk[0][1], nk[1][0], nk[1][1],
                       nk[2][0], nk[2][1], nk[3][0], nk[3][1]);
  }
}